// Round 5
// baseline (263.112 us; speedup 1.0000x reference)
//
#include <hip/hip_runtime.h>
#include <stdint.h>

// WeightsDropout: per row of 4096 f32 (uniform in (1e-4,1)), drop the 2048
// smallest (stable tie-break: smaller index dropped first), softmax survivors.
//
// R5: overlap-first. Persistent blocks: 4 rows/block with register prefetch
// (row r+1's loads issued before row r's selection phases -> HBM latency
// hidden under compute), grid = 2048 = 8 blocks/CU, __launch_bounds__(256,8)
// to force VGPR<=64 so 32 waves/CU are resident (R4 ran at 48% occupancy).
// Selection = R4's band histogram (k-th stat of uniform data lies in
// [0.45,0.55) whp; ~410 elems histogrammed into 256 buckets, exact
// lex-(bits,idx) rank in the crossing bucket) + exact block-uniform
// bisection fallback for arbitrary data.
constexpr int N     = 4096;
constexpr int KSEL  = 2048;          // int(N * 0.5)
constexpr int BLOCK = 256;
constexpr int NW    = BLOCK / 64;    // 4 waves
constexpr int EPT   = N / BLOCK;     // 16 elements/thread/row
constexpr int RPB   = 4;             // rows per block (pipelined)
constexpr int NB    = 256;           // fine buckets over the band
constexpr int CAP   = 128;           // candidate capacity (E[#]=1.6)
constexpr float P1  = 0.45f;
constexpr float P2  = 0.55f;
constexpr float BSCALE = 2560.0f;    // NB / (P2 - P1)

__global__ __launch_bounds__(BLOCK, 8)
void wdrop_kernel(const float* __restrict__ w, float* __restrict__ out) {
    const int t = threadIdx.x, wid = t >> 6, lane = t & 63;
    const uint64_t row0 = (uint64_t)blockIdx.x * RPB;

    __shared__ int      hist[NB];
    __shared__ uint32_t redu[NW];
    __shared__ int      redi[NW];
    __shared__ float    redf[NW];
    __shared__ int      scanw[NW];
    __shared__ int      selb, selc, cn;
    __shared__ uint32_t cbv[CAP];
    __shared__ int      civ[CAP];
    __shared__ uint32_t thrT, thrI;

    // prefetch row 0
    uint4 nb[EPT / 4];
    {
        const uint4* wf = (const uint4*)(w + row0 * N);
#pragma unroll
        for (int j = 0; j < EPT / 4; ++j) nb[j] = wf[j * BLOCK + t];
    }

    for (int r = 0; r < RPB; ++r) {
        // ---- unpack current row (vmcnt wait here), then immediately issue next row's loads
        uint32_t v[EPT];
#pragma unroll
        for (int j = 0; j < EPT / 4; ++j) {
            v[4*j+0] = nb[j].x; v[4*j+1] = nb[j].y; v[4*j+2] = nb[j].z; v[4*j+3] = nb[j].w;
        }
        if (r + 1 < RPB) {
            const uint4* wn = (const uint4*)(w + (row0 + r + 1) * N);
#pragma unroll
            for (int j = 0; j < EPT / 4; ++j) nb[j] = wn[j * BLOCK + t];
        }
        hist[t] = 0;                       // NB == BLOCK
        if (t == 0) cn = 0;

        // ---- row max + band counts (clo=#(<P1), chi=#(<P2)) packed wave reduce
        uint32_t mx = v[0];
        int clo = 0, chi = 0;
#pragma unroll
        for (int e = 0; e < EPT; ++e) {
            mx = max(mx, v[e]);
            const float f = __uint_as_float(v[e]);
            clo += (f < P1); chi += (f < P2);
        }
        int pk = (clo << 16) | chi;
#pragma unroll
        for (int off = 32; off > 0; off >>= 1) {
            mx = max(mx, (uint32_t)__shfl_xor((int)mx, off, 64));
            pk += __shfl_xor(pk, off, 64);
        }
        if (lane == 0) { redu[wid] = mx; redi[wid] = pk; }
        __syncthreads();                                      // B
        uint32_t mxb = redu[0]; int pks = redi[0];
#pragma unroll
        for (int i = 1; i < NW; ++i) { mxb = max(mxb, redu[i]); pks += redi[i]; }
        const int clo_b = pks >> 16, chi_b = pks & 0xFFFF;
        bool fast = (clo_b < KSEL) && (chi_b >= KSEL);        // block-uniform
        const int jrank = KSEL - clo_b;

        if (fast) {
            // ---- band histogram (~10% of elements)
#pragma unroll
            for (int e = 0; e < EPT; ++e) {
                const float f = __uint_as_float(v[e]);
                if (f >= P1 && f < P2)
                    atomicAdd(&hist[min((int)((f - P1) * BSCALE), NB - 1)], 1);
            }
            __syncthreads();                                  // C
            // ---- scan (one bucket/thread) -> crossing bucket
            const int h = hist[t];
            int sc = h;
#pragma unroll
            for (int off = 1; off < 64; off <<= 1) {
                const int u = __shfl_up(sc, off, 64);
                if (lane >= off) sc += u;
            }
            if (lane == 63) scanw[wid] = sc;
            __syncthreads();                                  // D
            int wb = 0;
#pragma unroll
            for (int i = 0; i < NW; ++i) if (i < wid) wb += scanw[i];
            const int inc = sc + wb, exc = inc - h;
            if (exc < jrank && jrank <= inc) { selb = t; selc = exc; }
            __syncthreads();                                  // E
            // ---- gather candidates in crossing bucket
            const int bs = selb;
#pragma unroll
            for (int e = 0; e < EPT; ++e) {
                const float f = __uint_as_float(v[e]);
                if (f >= P1 && f < P2 && min((int)((f - P1) * BSCALE), NB - 1) == bs) {
                    const int slot = atomicAdd(&cn, 1);
                    if (slot < CAP) {
                        cbv[slot] = v[e];
                        civ[slot] = ((e >> 2) * BLOCK + t) * 4 + (e & 3);
                    }
                }
            }
            __syncthreads();                                  // F
            if (cn <= CAP) {
                // ---- exact lex-(bits,idx) rank among candidates
                if (t < cn) {
                    const uint32_t myb = cbv[t]; const int myi = civ[t];
                    int rank = 0;
                    for (int q = 0; q < cn; ++q)
                        rank += (cbv[q] < myb) || (cbv[q] == myb && civ[q] < myi);
                    if (rank == jrank - selc - 1) { thrT = myb; thrI = (uint32_t)myi; }
                }
            } else fast = false;                              // cn is LDS: block-uniform
            __syncthreads();                                  // G
        }

        if (!fast) {
            // ---- exact fallback: bisection on value bits, then on index (ties)
            uint32_t blo = 0u, bhi = 0x7f7fffffu;
            while (blo < bhi) {
                const uint32_t mid = blo + ((bhi - blo) >> 1);
                int c = 0;
#pragma unroll
                for (int e = 0; e < EPT; ++e) c += __popcll(__ballot(v[e] <= mid));
                __syncthreads();
                if (lane == 0) redi[wid] = c;
                __syncthreads();
                int tot = 0;
#pragma unroll
                for (int i = 0; i < NW; ++i) tot += redi[i];
                if (tot >= KSEL) bhi = mid; else blo = mid + 1;
            }
            const uint32_t T = blo;
            int c = 0;
#pragma unroll
            for (int e = 0; e < EPT; ++e) c += __popcll(__ballot(v[e] < T));
            __syncthreads();
            if (lane == 0) redi[wid] = c;
            __syncthreads();
            int clt = 0;
#pragma unroll
            for (int i = 0; i < NW; ++i) clt += redi[i];
            const int need = KSEL - clt;
            int ilo = 0, ihi = N - 1;
            while (ilo < ihi) {
                const int imid = (ilo + ihi) >> 1;
                int cc = 0;
#pragma unroll
                for (int e = 0; e < EPT; ++e) {
                    const int idx = ((e >> 2) * BLOCK + t) * 4 + (e & 3);
                    cc += __popcll(__ballot(v[e] == T && idx <= imid));
                }
                __syncthreads();
                if (lane == 0) redi[wid] = cc;
                __syncthreads();
                int tot = 0;
#pragma unroll
                for (int i = 0; i < NW; ++i) tot += redi[i];
                if (tot >= need) ihi = imid; else ilo = imid + 1;
            }
            if (t == 0) { thrT = T; thrI = (uint32_t)ilo; }
            __syncthreads();
        }

        // ---- keep + exp + block sum, scale, store
        const uint32_t T = thrT; const int ti = (int)thrI;
        const float m = __uint_as_float(mxb);
        float acc = 0.0f;
#pragma unroll
        for (int e = 0; e < EPT; ++e) {
            const int idx = ((e >> 2) * BLOCK + t) * 4 + (e & 3);
            const bool keep = (v[e] > T) || (v[e] == T && idx > ti);
            const float ev = keep ? __expf(__uint_as_float(v[e]) - m) : 0.0f;
            v[e] = __float_as_uint(ev);
            acc += ev;
        }
#pragma unroll
        for (int off = 32; off > 0; off >>= 1) acc += __shfl_xor(acc, off, 64);
        if (lane == 0) redf[wid] = acc;
        __syncthreads();                                      // H (also protects LDS reuse)
        float tot = 0.0f;
#pragma unroll
        for (int i = 0; i < NW; ++i) tot += redf[i];
        const float inv = 1.0f / tot;
        uint4* of = (uint4*)(out + (row0 + r) * N);
#pragma unroll
        for (int j = 0; j < EPT / 4; ++j) {
            float4 o;
            o.x = __uint_as_float(v[4*j+0]) * inv;
            o.y = __uint_as_float(v[4*j+1]) * inv;
            o.z = __uint_as_float(v[4*j+2]) * inv;
            o.w = __uint_as_float(v[4*j+3]) * inv;
            ((float4*)of)[j * BLOCK + t] = o;
        }
    }
}

extern "C" void kernel_launch(void* const* d_in, const int* in_sizes, int n_in,
                              void* d_out, int out_size, void* d_ws, size_t ws_size,
                              hipStream_t stream) {
    const float* w = (const float*)d_in[0];
    float* out = (float*)d_out;
    const int rows = in_sizes[0] / N;              // 8192
    wdrop_kernel<<<rows / RPB, BLOCK, 0, stream>>>(w, out);
}